// Round 1
// baseline (57.195 us; speedup 1.0000x reference)
//
#include <hip/hip_runtime.h>
#include <math.h>

#define BLOCK 256
#define C_CLS 80
#define G_MAX 256

static __device__ inline float frcp(float x) { return __builtin_amdgcn_rcpf(x); }

__global__ __launch_bounds__(BLOCK) void detloss_main(
    const float* __restrict__ anchors,    // [A,4]
    const float* __restrict__ cls_logits, // [A,C]
    const float* __restrict__ bbox_reg,   // [A,4]
    const float* __restrict__ centerness, // [A]
    const float* __restrict__ gt_boxes,   // [G,4]
    const int*   __restrict__ gt_labels,  // [G]
    float* __restrict__ sums,             // [4]: sum(af*fl), npos, sum(pos*giou), sum(pos*bce)
    int A, int G)
{
    __shared__ float4 s_gt[G_MAX];
    __shared__ float  s_ga[G_MAX];
    __shared__ int    s_gl[G_MAX];
    const int tid = threadIdx.x;
    for (int j = tid; j < G; j += BLOCK) {
        float4 g = reinterpret_cast<const float4*>(gt_boxes)[j];
        s_gt[j] = g;
        s_ga[j] = (g.z - g.x) * (g.w - g.y);
        s_gl[j] = gt_labels[j];
    }
    __syncthreads();

    const int a = blockIdx.x * BLOCK + tid;
    float c_affl = 0.f, c_pos = 0.f, c_giou = 0.f, c_bce = 0.f;

    if (a < A) {
        const float4 ab = reinterpret_cast<const float4*>(anchors)[a];
        const float area_a = (ab.z - ab.x) * (ab.w - ab.y);

        // ---- argmax IoU over G (first-occurrence semantics: strict >) ----
        float best = -1.0f;
        int   bidx = 0;
        for (int j = 0; j < G; ++j) {
            const float4 g = s_gt[j];
            const float lx = fmaxf(ab.x, g.x);
            const float ly = fmaxf(ab.y, g.y);
            const float rx = fminf(ab.z, g.z);
            const float ry = fminf(ab.w, g.w);
            const float iw = fmaxf(rx - lx, 0.0f);
            const float ih = fmaxf(ry - ly, 0.0f);
            const float inter = iw * ih;
            const float iou = inter * frcp(area_a + s_ga[j] - inter);
            if (iou > best) { best = iou; bidx = j; }
        }
        const bool  pos  = best > 0.5f;
        const float posf = pos ? 1.0f : 0.0f;
        const float4 mb  = s_gt[bidx];
        const int   mlab = s_gl[bidx];

        // ---- focal loss: online logsumexp over the 80-class row ----
        const float4* row4 = reinterpret_cast<const float4*>(cls_logits + (size_t)a * C_CLS);
        float m = -3.4e38f, s = 0.0f;
        #pragma unroll
        for (int k = 0; k < C_CLS / 4; ++k) {
            const float4 v = row4[k];
            const float m4 = fmaxf(fmaxf(v.x, v.y), fmaxf(v.z, v.w));
            const float mn = fmaxf(m, m4);
            s = s * __expf(m - mn)
              + __expf(v.x - mn) + __expf(v.y - mn)
              + __expf(v.z - mn) + __expf(v.w - mn);
            m = mn;
        }
        const float lse = m + __logf(s);
        // python-style (-1 % C) == C-1 gather
        const int   cls_t = pos ? mlab : -1;
        const int   gidx  = pos ? mlab : (C_CLS - 1);
        const float l_idx = cls_logits[(size_t)a * C_CLS + gidx];
        const float ce = lse - l_idx;
        const float p  = __expf(-ce);
        const float om = 1.0f - p;
        const float fl = om * om * ce;
        const float af = (cls_t == 1) ? 0.25f : 0.75f;
        c_affl = af * fl;

        // ---- decode pred box ----
        const float w  = ab.z - ab.x;
        const float h  = ab.w - ab.y;
        const float cx = ab.x + 0.5f * w;
        const float cy = ab.y + 0.5f * h;
        const float4 t = reinterpret_cast<const float4*>(bbox_reg)[a];
        const float pcx = cx + t.x * w;
        const float pcy = cy + t.y * h;
        const float pw  = __expf(t.z * w) * w;
        const float ph  = __expf(t.w * h) * h;
        const float p0 = pcx - 0.5f * pw;
        const float p1 = pcy - 0.5f * ph;
        const float p2 = pcx + 0.5f * pw;
        const float p3 = pcy + 0.5f * ph;

        // ---- paired GIoU with matched box ----
        const float lx2 = fmaxf(p0, mb.x);
        const float ly2 = fmaxf(p1, mb.y);
        const float rx2 = fminf(p2, mb.z);
        const float ry2 = fminf(p3, mb.w);
        const float iw2 = fmaxf(rx2 - lx2, 0.0f);
        const float ih2 = fmaxf(ry2 - ly2, 0.0f);
        const float inter2 = iw2 * ih2;
        const float area_p = (p2 - p0) * (p3 - p1);
        const float area_m = (mb.z - mb.x) * (mb.w - mb.y);
        const float uni = area_p + area_m - inter2;
        const float iou2 = inter2 * frcp(uni);
        const float elx = fminf(p0, mb.x);
        const float ely = fminf(p1, mb.y);
        const float erx = fmaxf(p2, mb.z);
        const float ery = fmaxf(p3, mb.w);
        const float ew = fmaxf(erx - elx, 0.0f);
        const float eh = fmaxf(ery - ely, 0.0f);
        const float earea = ew * eh;
        const float giou = iou2 - (earea - uni) * frcp(earea);
        c_giou = posf * giou;

        // ---- centerness target + BCE ----
        const float lr0 = mb.x - ab.x;
        const float lr1 = mb.z - ab.z;
        const float tb0 = mb.y - ab.y;
        const float tb1 = mb.w - ab.w;
        const float lrmax = fmaxf(lr0, lr1);
        const float lrmin = fminf(lr0, lr1);
        const float tbmax = fmaxf(tb0, tb1);
        const float tbmin = fminf(tb0, tb1);
        const float r_lr = fmaxf(lrmin * frcp(lrmax == 0.0f ? 1.0f : lrmax), 0.0f);
        const float r_tb = fmaxf(tbmin * frcp(tbmax == 0.0f ? 1.0f : tbmax), 0.0f);
        const float ctr_t = sqrtf(fmaxf(r_lr * r_tb, 1e-12f));
        const float c = centerness[a];
        const float bce = fmaxf(c, 0.0f) + log1pf(__expf(-fabsf(c))) - c * ctr_t;
        c_bce = posf * bce;
        c_pos = posf;
    }

    // ---- block reduction: 4 values, wave shuffle then cross-wave LDS ----
    __shared__ float red[4][BLOCK / 64];
    float vals[4] = { c_affl, c_pos, c_giou, c_bce };
    #pragma unroll
    for (int i = 0; i < 4; ++i) {
        float v = vals[i];
        #pragma unroll
        for (int off = 32; off > 0; off >>= 1) v += __shfl_down(v, off, 64);
        if ((tid & 63) == 0) red[i][tid >> 6] = v;
    }
    __syncthreads();
    if (tid < 4) {
        float v = 0.f;
        #pragma unroll
        for (int wv = 0; wv < BLOCK / 64; ++wv) v += red[tid][wv];
        atomicAdd(&sums[tid], v);
    }
}

__global__ void detloss_final(const float* __restrict__ sums,
                              float* __restrict__ out, int A)
{
    const float s_affl = sums[0];
    const float npos   = sums[1];
    const float sgiou  = sums[2];
    const float sbce   = sums[3];
    float cls = s_affl / (float)A;
    const float denom = fmaxf(npos, 1.0f);
    float reg = 1.0f - sgiou / denom;
    float ctr = sbce / denom;
    const float has = (npos > 0.0f) ? 1.0f : 0.0f;
    cls *= has; reg *= has; ctr *= has;
    out[0] = cls + reg + ctr;
    out[1] = cls;
    out[2] = reg;
    out[3] = ctr;
}

extern "C" void kernel_launch(void* const* d_in, const int* in_sizes, int n_in,
                              void* d_out, int out_size, void* d_ws, size_t ws_size,
                              hipStream_t stream) {
    const float* anchors    = (const float*)d_in[0];
    const float* cls_logits = (const float*)d_in[1];
    const float* bbox_reg   = (const float*)d_in[2];
    const float* centerness = (const float*)d_in[3];
    const float* gt_boxes   = (const float*)d_in[4];
    const int*   gt_labels  = (const int*)d_in[5];
    const int A = in_sizes[0] / 4;
    int G = in_sizes[4] / 4;
    if (G > G_MAX) G = G_MAX;

    float* sums = (float*)d_ws;
    hipMemsetAsync(sums, 0, 4 * sizeof(float), stream);

    const int grid = (A + BLOCK - 1) / BLOCK;
    detloss_main<<<grid, BLOCK, 0, stream>>>(anchors, cls_logits, bbox_reg,
                                             centerness, gt_boxes, gt_labels,
                                             sums, A, G);
    detloss_final<<<1, 1, 0, stream>>>(sums, (float*)d_out, A);
}